// Round 1
// baseline (673.194 us; speedup 1.0000x reference)
//
#include <hip/hip_runtime.h>
#include <hip/hip_bf16.h>
#include <stdint.h>

// Problem constants (from reference): B=4, S=2048, D=1024, H=16, DK=64
#define S_LEN 2048
#define D_DIM 1024
#define NH    16
#define DKH   64
#define BATCH 4

typedef __bf16 bf16x8 __attribute__((ext_vector_type(8)));
typedef float  f32x4  __attribute__((ext_vector_type(4)));

__device__ __forceinline__ unsigned short f2bf(float x) {
  unsigned u = __float_as_uint(x);
  return (unsigned short)((u + 0x7FFFu + ((u >> 16) & 1u)) >> 16);  // RNE
}
__device__ __forceinline__ float bf2f(unsigned short b) {
  return __uint_as_float(((unsigned)b) << 16);
}

// async global->LDS, 16B per lane. LDS dest is wave-uniform base + lane*16.
__device__ __forceinline__ void gll16(const void* g, void* l) {
  __builtin_amdgcn_global_load_lds((const __attribute__((address_space(1))) unsigned*)g,
                                   (__attribute__((address_space(3))) unsigned*)l, 16, 0, 0);
}

#define MFMA(a, b, c) __builtin_amdgcn_mfma_f32_16x16x32_bf16(a, b, c, 0, 0, 0)

// ---------------------------------------------------------------------------
// Convert fp32 -> bf16 hi/lo, elementwise (for X / inputs), 4 floats/thread
// ---------------------------------------------------------------------------
__global__ void k_split(const float4* __restrict__ x, ushort4* __restrict__ hi,
                        ushort4* __restrict__ lo, int n4) {
  int i = blockIdx.x * 256 + threadIdx.x;
  if (i >= n4) return;
  float4 v = x[i];
  ushort4 h, l;
  h.x = f2bf(v.x); l.x = f2bf(v.x - bf2f(h.x));
  h.y = f2bf(v.y); l.y = f2bf(v.y - bf2f(h.y));
  h.z = f2bf(v.z); l.z = f2bf(v.z - bf2f(h.z));
  h.w = f2bf(v.w); l.w = f2bf(v.w - bf2f(h.w));
  hi[i] = h;
  lo[i] = l;
}

// ---------------------------------------------------------------------------
// Convert + transpose weight: W[K][N] fp32 -> Wt hi/lo [N][K] bf16
// 64x64 tiles, LDS transpose (padded to avoid bank conflicts)
// ---------------------------------------------------------------------------
__global__ void k_wt(const float* __restrict__ W, unsigned short* __restrict__ hi,
                     unsigned short* __restrict__ lo) {
  __shared__ float t[64][65];
  const int tid = threadIdx.x;
  const int k0 = blockIdx.x * 64, n0 = blockIdx.y * 64;
#pragma unroll
  for (int i = 0; i < 16; i++) {
    int idx = i * 256 + tid;
    int r = idx >> 6, c = idx & 63;
    t[r][c] = W[(size_t)(k0 + r) * D_DIM + n0 + c];
  }
  __syncthreads();
#pragma unroll
  for (int i = 0; i < 16; i++) {
    int idx = i * 256 + tid;
    int r = idx >> 6, c = idx & 63;
    float v = t[c][r];  // = W[k0+c][n0+r]
    unsigned short h = f2bf(v);
    size_t o = (size_t)(n0 + r) * D_DIM + k0 + c;
    hi[o] = h;
    lo[o] = f2bf(v - bf2f(h));
  }
}

// ---------------------------------------------------------------------------
// hi/lo split GEMM: C[M,N] = A[M,K] * B[K,N], B given transposed as Bt[N][K].
// M=8192, N=K=1024. 128x128 tile, BK=64, 4 waves (2x2 of 64x64), 3-pass MFMA.
// MODE 0: write C as hi/lo bf16 [M][N]           (Q, K projections)
// MODE 1: write C as hi/lo bf16 transposed per-head Vt[b][h][d][s]  (V proj)
// MODE 2: write C as fp32 [M][N]                  (final O @ Wo)
// LDS: 4 tiles x 16KB (XOR-swizzled chunk layout), single-buffered.
// ---------------------------------------------------------------------------
template <int MODE>
__global__ __launch_bounds__(256, 2) void gemm_hilo(
    const unsigned short* __restrict__ Ahi, const unsigned short* __restrict__ Alo,
    const unsigned short* __restrict__ Bth, const unsigned short* __restrict__ Btl,
    unsigned short* __restrict__ Chi, unsigned short* __restrict__ Clo,
    float* __restrict__ Cf) {
  constexpr int N = 1024, K = 1024;
  extern __shared__ char smem[];
  char* sAh = smem;
  char* sAl = smem + 16384;
  char* sBh = smem + 32768;
  char* sBl = smem + 49152;

  const int tid = threadIdx.x;
  const int lane = tid & 63, w = tid >> 6;
  const int wr = w >> 1, wc = w & 1;
  const int m0 = blockIdx.y * 128, n0 = blockIdx.x * 128;

  // staging: tile = 128 rows x 8 chunks(16B). chunk c -> row=c>>3, slot s=c&7.
  // LDS slot (row,s) holds global chunk (row, s^(row&7))  [XOR swizzle]
  int gofs[4], lofs[4];
#pragma unroll
  for (int i = 0; i < 4; i++) {
    int c = (w * 4 + i) * 64 + lane;
    int row = c >> 3, s = c & 7;
    int sp = s ^ (row & 7);
    gofs[i] = row * K + sp * 8;  // element offset within tile
    lofs[i] = (w * 4 + i) * 1024;  // byte offset (wave-uniform base)
  }
  const unsigned short* pAh = Ahi + (size_t)m0 * K;
  const unsigned short* pAl = Alo + (size_t)m0 * K;
  const unsigned short* pBh = Bth + (size_t)n0 * K;
  const unsigned short* pBl = Btl + (size_t)n0 * K;

  f32x4 acc[4][4] = {};

  for (int kt = 0; kt < K / 64; ++kt) {
    const int ko = kt * 64;
#pragma unroll
    for (int i = 0; i < 4; i++) {
      gll16(pAh + ko + gofs[i], sAh + lofs[i]);
      gll16(pAl + ko + gofs[i], sAl + lofs[i]);
      gll16(pBh + ko + gofs[i], sBh + lofs[i]);
      gll16(pBl + ko + gofs[i], sBl + lofs[i]);
    }
    __syncthreads();
#pragma unroll
    for (int kk = 0; kk < 2; kk++) {
      bf16x8 ah[4], al[4], bh[4], bl[4];
      const int cch = kk * 4 + (lane >> 4);
#pragma unroll
      for (int mr = 0; mr < 4; mr++) {
        int row = wr * 64 + mr * 16 + (lane & 15);
        int off = row * 128 + ((cch ^ (row & 7)) << 4);
        ah[mr] = *(const bf16x8*)(sAh + off);
        al[mr] = *(const bf16x8*)(sAl + off);
      }
#pragma unroll
      for (int nr = 0; nr < 4; nr++) {
        int row = wc * 64 + nr * 16 + (lane & 15);
        int off = row * 128 + ((cch ^ (row & 7)) << 4);
        bh[nr] = *(const bf16x8*)(sBh + off);
        bl[nr] = *(const bf16x8*)(sBl + off);
      }
#pragma unroll
      for (int mr = 0; mr < 4; mr++)
#pragma unroll
        for (int nr = 0; nr < 4; nr++) {
          acc[mr][nr] = MFMA(ah[mr], bh[nr], acc[mr][nr]);
          acc[mr][nr] = MFMA(ah[mr], bl[nr], acc[mr][nr]);
          acc[mr][nr] = MFMA(al[mr], bh[nr], acc[mr][nr]);
        }
    }
    __syncthreads();
  }

  // epilogue: C/D layout col=lane&15, row=(lane>>4)*4+j
#pragma unroll
  for (int mr = 0; mr < 4; mr++)
#pragma unroll
    for (int nr = 0; nr < 4; nr++)
#pragma unroll
      for (int j = 0; j < 4; j++) {
        int row = m0 + wr * 64 + mr * 16 + (lane >> 4) * 4 + j;
        int col = n0 + wc * 64 + nr * 16 + (lane & 15);
        float v = acc[mr][nr][j];
        if constexpr (MODE == 0) {
          size_t o = (size_t)row * N + col;
          unsigned short h = f2bf(v);
          Chi[o] = h;
          Clo[o] = f2bf(v - bf2f(h));
        } else if constexpr (MODE == 1) {
          int bi = row >> 11, s = row & (S_LEN - 1);
          int hh = col >> 6, d = col & (DKH - 1);
          size_t o = ((size_t)(bi * NH + hh) * DKH + d) * S_LEN + s;
          unsigned short h = f2bf(v);
          Chi[o] = h;
          Clo[o] = f2bf(v - bf2f(h));
        } else {
          Cf[(size_t)row * N + col] = v;
        }
      }
}

// ---------------------------------------------------------------------------
// Flash attention: per block = one (b,h), 64 q rows; 4 waves x 16 q rows.
// K-tiles of 64 keys. hi/lo 3-pass MFMA for QK^T and PV. Online softmax.
// Q hi/lo layout [B,S,D] (head-contiguous), Vt hi/lo [B,H,DK,S].
// Output O hi/lo [B,S,D].
// ---------------------------------------------------------------------------
__global__ __launch_bounds__(256, 2) void attn(
    const unsigned short* __restrict__ Qh, const unsigned short* __restrict__ Ql,
    const unsigned short* __restrict__ Kh, const unsigned short* __restrict__ Kl,
    const unsigned short* __restrict__ Vth, const unsigned short* __restrict__ Vtl,
    const int* __restrict__ mask, unsigned short* __restrict__ Oh,
    unsigned short* __restrict__ Ol) {
  extern __shared__ char smem[];
  char* sKh = smem;            // [64][64] bf16, swizzled, 8KB
  char* sKl = smem + 8192;
  char* sVh = smem + 16384;    // Vt tile [d:64][s:64]
  char* sVl = smem + 24576;
  const int tid = threadIdx.x, lane = tid & 63, w = tid >> 6;
  char* sP = smem + 32768 + w * 4096;  // per-wave P hi [16][64] + lo (+2048)

  const int q0 = blockIdx.x * 64;
  const int bh = blockIdx.y;
  const int b = bh >> 4, h = bh & (NH - 1);

  // Q fragments (A-operand): row=lane&15, k=(lane>>4)*8 + kk*32
  bf16x8 qh[2], ql[2];
  {
    int row = q0 + w * 16 + (lane & 15);
    size_t base = ((size_t)(b * S_LEN + row)) * D_DIM + h * DKH + (lane >> 4) * 8;
    qh[0] = *(const bf16x8*)(Qh + base);
    qh[1] = *(const bf16x8*)(Qh + base + 32);
    ql[0] = *(const bf16x8*)(Ql + base);
    ql[1] = *(const bf16x8*)(Ql + base + 32);
  }

  float mrow[4] = {-1e30f, -1e30f, -1e30f, -1e30f};
  float lrow[4] = {0.f, 0.f, 0.f, 0.f};
  f32x4 oacc[4] = {};

  for (int kt = 0; kt < S_LEN / 64; ++kt) {
    const int sk0 = kt * 64;
    // stage K hi/lo and Vt hi/lo tiles (512 chunks each / 4 waves = 2 iters)
#pragma unroll
    for (int i = 0; i < 2; i++) {
      int c = (w * 2 + i) * 64 + lane;
      int row = c >> 3, s = c & 7;
      int sp = s ^ (row & 7);
      int lo_ = (w * 2 + i) * 1024;
      size_t gk = ((size_t)(b * S_LEN + sk0 + row)) * D_DIM + h * DKH + sp * 8;
      gll16(Kh + gk, sKh + lo_);
      gll16(Kl + gk, sKl + lo_);
      size_t gv = ((size_t)(bh * DKH + row)) * S_LEN + sk0 + sp * 8;
      gll16(Vth + gv, sVh + lo_);
      gll16(Vtl + gv, sVl + lo_);
    }
    __syncthreads();

    // scores: 16 q rows x 64 keys
    f32x4 sc[4] = {};
#pragma unroll
    for (int kk = 0; kk < 2; kk++) {
      const int cch = kk * 4 + (lane >> 4);
      bf16x8 kfh[4], kfl[4];
#pragma unroll
      for (int nr = 0; nr < 4; nr++) {
        int row = nr * 16 + (lane & 15);
        int off = row * 128 + ((cch ^ (row & 7)) << 4);
        kfh[nr] = *(const bf16x8*)(sKh + off);
        kfl[nr] = *(const bf16x8*)(sKl + off);
      }
#pragma unroll
      for (int nr = 0; nr < 4; nr++) {
        sc[nr] = MFMA(qh[kk], kfh[nr], sc[nr]);
        sc[nr] = MFMA(qh[kk], kfl[nr], sc[nr]);
        sc[nr] = MFMA(ql[kk], kfh[nr], sc[nr]);
      }
    }

    // scale + mask
    float p[4][4];
#pragma unroll
    for (int nr = 0; nr < 4; nr++) {
      int mv = mask[b * S_LEN + sk0 + nr * 16 + (lane & 15)];
      float madd = mv ? 0.f : -1e9f;
#pragma unroll
      for (int j = 0; j < 4; j++) p[nr][j] = sc[nr][j] * 0.125f + madd;
    }

    // online softmax (rows j; reduce over 16-lane col groups)
#pragma unroll
    for (int j = 0; j < 4; j++) {
      float rm = fmaxf(fmaxf(p[0][j], p[1][j]), fmaxf(p[2][j], p[3][j]));
      rm = fmaxf(rm, __shfl_xor(rm, 1));
      rm = fmaxf(rm, __shfl_xor(rm, 2));
      rm = fmaxf(rm, __shfl_xor(rm, 4));
      rm = fmaxf(rm, __shfl_xor(rm, 8));
      float mn = fmaxf(mrow[j], rm);
      float al = __expf(mrow[j] - mn);
      mrow[j] = mn;
      lrow[j] *= al;
#pragma unroll
      for (int f = 0; f < 4; f++) oacc[f][j] *= al;
      float rs = 0.f;
#pragma unroll
      for (int nr = 0; nr < 4; nr++) {
        p[nr][j] = __expf(p[nr][j] - mn);
        rs += p[nr][j];
      }
      rs += __shfl_xor(rs, 1);
      rs += __shfl_xor(rs, 2);
      rs += __shfl_xor(rs, 4);
      rs += __shfl_xor(rs, 8);
      lrow[j] += rs;
    }

    // write P hi/lo to per-wave LDS (C-layout -> A-layout relayout), swizzled
#pragma unroll
    for (int nr = 0; nr < 4; nr++)
#pragma unroll
      for (int j = 0; j < 4; j++) {
        int row = (lane >> 4) * 4 + j, col = nr * 16 + (lane & 15);
        int off = row * 128 + ((col * 2) ^ ((row & 7) << 4));
        unsigned short hsh = f2bf(p[nr][j]);
        *(unsigned short*)(sP + off) = hsh;
        *(unsigned short*)(sP + 2048 + off) = f2bf(p[nr][j] - bf2f(hsh));
      }

    // PV: out[q][d] += P[q][sk] * V[sk][d]; B-frag from Vt[d][sk]
#pragma unroll
    for (int kk = 0; kk < 2; kk++) {
      const int cch = kk * 4 + (lane >> 4);
      int prow = lane & 15;
      int poff = prow * 128 + (((cch) << 4) ^ ((prow & 7) << 4));
      bf16x8 pfh = *(const bf16x8*)(sP + poff);
      bf16x8 pfl = *(const bf16x8*)(sP + 2048 + poff);
#pragma unroll
      for (int f = 0; f < 4; f++) {
        int vrow = f * 16 + (lane & 15);
        int voff = vrow * 128 + ((cch ^ (vrow & 7)) << 4);
        bf16x8 vfh = *(const bf16x8*)(sVh + voff);
        bf16x8 vfl = *(const bf16x8*)(sVl + voff);
        oacc[f] = MFMA(pfh, vfh, oacc[f]);
        oacc[f] = MFMA(pfh, vfl, oacc[f]);
        oacc[f] = MFMA(pfl, vfh, oacc[f]);
      }
    }
    __syncthreads();
  }

  // normalize + write O hi/lo [B,S,D]
  float inv[4];
#pragma unroll
  for (int j = 0; j < 4; j++) inv[j] = 1.f / lrow[j];
#pragma unroll
  for (int f = 0; f < 4; f++)
#pragma unroll
    for (int j = 0; j < 4; j++) {
      int row = q0 + w * 16 + (lane >> 4) * 4 + j;
      int col = h * DKH + f * 16 + (lane & 15);
      float v = oacc[f][j] * inv[j];
      size_t o = ((size_t)(b * S_LEN + row)) * D_DIM + col;
      unsigned short hh = f2bf(v);
      Oh[o] = hh;
      Ol[o] = f2bf(v - bf2f(hh));
    }
}

// ---------------------------------------------------------------------------
extern "C" void kernel_launch(void* const* d_in, const int* in_sizes, int n_in,
                              void* d_out, int out_size, void* d_ws, size_t ws_size,
                              hipStream_t stream) {
  const float* X = (const float*)d_in[0];
  const int* mask = (const int*)d_in[1];
  const float* Wq = (const float*)d_in[2];
  const float* Wk = (const float*)d_in[3];
  const float* Wv = (const float*)d_in[4];
  const float* Wo = (const float*)d_in[5];
  float* out = (float*)d_out;

  const size_t MB = 1024 * 1024;
  if (ws_size < 144 * MB) return;  // insufficient scratch -> visible failure

  char* ws = (char*)d_ws;
  // layout (bf16 = ushort). X region is reused for attention output O.
  unsigned short* Xh = (unsigned short*)(ws);            // 16MB  (later Oh)
  unsigned short* Xl = (unsigned short*)(ws + 16 * MB);  // 16MB  (later Ol)
  unsigned short* Wqth = (unsigned short*)(ws + 32 * MB);
  unsigned short* Wqtl = Wqth + 1024 * 1024;
  unsigned short* Wkth = Wqtl + 1024 * 1024;
  unsigned short* Wktl = Wkth + 1024 * 1024;
  unsigned short* Wvth = Wktl + 1024 * 1024;
  unsigned short* Wvtl = Wvth + 1024 * 1024;
  unsigned short* Woth = Wvtl + 1024 * 1024;
  unsigned short* Wotl = Woth + 1024 * 1024;             // ends at 48MB
  unsigned short* Qh = (unsigned short*)(ws + 48 * MB);
  unsigned short* Ql = (unsigned short*)(ws + 64 * MB);
  unsigned short* Kh = (unsigned short*)(ws + 80 * MB);
  unsigned short* Kl = (unsigned short*)(ws + 96 * MB);
  unsigned short* Vth = (unsigned short*)(ws + 112 * MB);
  unsigned short* Vtl = (unsigned short*)(ws + 128 * MB);

  const int n4 = BATCH * S_LEN * D_DIM / 4;  // 2097152
  k_split<<<(n4 + 255) / 256, 256, 0, stream>>>((const float4*)X, (ushort4*)Xh,
                                                (ushort4*)Xl, n4);
  dim3 wtg(16, 16);
  k_wt<<<wtg, 256, 0, stream>>>(Wq, Wqth, Wqtl);
  k_wt<<<wtg, 256, 0, stream>>>(Wk, Wkth, Wktl);
  k_wt<<<wtg, 256, 0, stream>>>(Wv, Wvth, Wvtl);
  k_wt<<<wtg, 256, 0, stream>>>(Wo, Woth, Wotl);

  dim3 gg(8, 64);  // N/128 x M/128
  gemm_hilo<0><<<gg, 256, 65536, stream>>>(Xh, Xl, Wqth, Wqtl, Qh, Ql, nullptr);
  gemm_hilo<0><<<gg, 256, 65536, stream>>>(Xh, Xl, Wkth, Wktl, Kh, Kl, nullptr);
  gemm_hilo<1><<<gg, 256, 65536, stream>>>(Xh, Xl, Wvth, Wvtl, Vth, Vtl, nullptr);

  dim3 ag(S_LEN / 64, BATCH * NH);  // 32 x 64
  attn<<<ag, 256, 49152, stream>>>(Qh, Ql, Kh, Kl, Vth, Vtl, mask, Xh, Xl);

  gemm_hilo<2><<<gg, 256, 65536, stream>>>(Xh, Xl, Woth, Wotl, nullptr, nullptr, out);
}